// Round 4
// baseline (299.975 us; speedup 1.0000x reference)
//
#include <hip/hip_runtime.h>
#include <hip/hip_bf16.h>
#include <math.h>

#define N_NODES 50000
#define N_EDGES 800000
#define IN_F 256
#define OUT_F 64

__device__ __forceinline__ float bf_lo(uint v) { return __uint_as_float(v << 16); }
__device__ __forceinline__ float bf_hi(uint v) { return __uint_as_float(v & 0xffff0000u); }

// ---------------------------------------------------------------------------
// 1) Degree counting: one thread per edge, int atomics.
// ---------------------------------------------------------------------------
__global__ __launch_bounds__(256) void deg_kernel(const int* __restrict__ src,
                                                  const int* __restrict__ dst,
                                                  int* __restrict__ outdeg,
                                                  int* __restrict__ indeg) {
    int i = blockIdx.x * blockDim.x + threadIdx.x;
    if (i < N_EDGES) {
        atomicAdd(&outdeg[src[i]], 1);
        atomicAdd(&indeg[dst[i]], 1);
    }
}

// ---------------------------------------------------------------------------
// 2) Bucket allocation: wave prefix-sum of indeg + one atomicAdd per wave.
//    Bucket order is arbitrary; gather only needs [beg, beg+deg).
// ---------------------------------------------------------------------------
__global__ __launch_bounds__(256) void alloc_kernel(const int* __restrict__ indeg,
                                                    int* __restrict__ ptrB,
                                                    int* __restrict__ cursor,
                                                    int* __restrict__ counter) {
    const int i = blockIdx.x * blockDim.x + threadIdx.x;
    const int lane = threadIdx.x & 63;
    const int v = (i < N_NODES) ? indeg[i] : 0;
    int incl = v;
    #pragma unroll
    for (int d = 1; d < 64; d <<= 1) {
        int u = __shfl_up(incl, d, 64);
        if (lane >= d) incl += u;
    }
    int base = 0;
    if (lane == 63) base = atomicAdd(counter, incl);
    base = __shfl(base, 63, 64);
    const int beg = base + incl - v;
    if (i < N_NODES) { ptrB[i] = beg; cursor[i] = beg; }
}

// ---------------------------------------------------------------------------
// 3) Bucket edges by dst: sorted_src[cursor[d]++] = src.
// ---------------------------------------------------------------------------
__global__ __launch_bounds__(256) void sort_kernel(const int* __restrict__ src,
                                                   const int* __restrict__ dst,
                                                   int* __restrict__ cursor,
                                                   int* __restrict__ sorted_src) {
    int e = blockIdx.x * blockDim.x + threadIdx.x;
    if (e < N_EDGES) {
        const int d = dst[e];
        const int idx = atomicAdd(&cursor[d], 1);
        sorted_src[idx] = src[e];
    }
}

// ---------------------------------------------------------------------------
// 4) h = bf16( (feat * norm_src) @ W ).
//    lane = row (per-lane float4 global loads, L1 column-walk, no LDS);
//    wave = 16 output cols; W loads are wave-uniform -> scalar s_load path;
//    inner loop is pure v_fmac with SGPR W operand.
// ---------------------------------------------------------------------------
__global__ __launch_bounds__(256) void gemm_kernel(const float* __restrict__ feat,
                                                   const float* __restrict__ W,
                                                   const int* __restrict__ outdeg,
                                                   ushort* __restrict__ h) {
    const int lane = threadIdx.x & 63;
    const int wave = threadIdx.x >> 6;
    const int col0 = wave * 16;
    const int row = blockIdx.x * 64 + lane;
    const bool valid = row < N_NODES;
    const float4* fp = (const float4*)(feat + (size_t)(valid ? row : 0) * IN_F);

    float acc[16];
    #pragma unroll
    for (int c = 0; c < 16; ++c) acc[c] = 0.f;

    #pragma unroll 2
    for (int k4 = 0; k4 < IN_F / 4; ++k4) {
        const float4 f = fp[k4];
        const float* wr = W + (size_t)k4 * 4 * OUT_F + col0;  // wave-uniform
        #pragma unroll
        for (int c = 0; c < 16; ++c) {
            acc[c] = fmaf(f.x, wr[c], acc[c]);
            acc[c] = fmaf(f.y, wr[OUT_F + c], acc[c]);
            acc[c] = fmaf(f.z, wr[2 * OUT_F + c], acc[c]);
            acc[c] = fmaf(f.w, wr[3 * OUT_F + c], acc[c]);
        }
    }

    if (valid) {
        const float norm = rsqrtf(fmaxf((float)outdeg[row], 1.0f));
        union { ushort u[16]; uint4 v[2]; } pk;
        #pragma unroll
        for (int c = 0; c < 16; ++c) {
            __hip_bfloat16 bb = __float2bfloat16(acc[c] * norm);
            pk.u[c] = *reinterpret_cast<ushort*>(&bb);
        }
        uint4* d4 = (uint4*)(h + (size_t)row * OUT_F + col0);
        d4[0] = pk.v[0];
        d4[1] = pk.v[1];
    }
}

// ---------------------------------------------------------------------------
// 5) Gather + epilogue: one wave per dst node, 2 edges per iteration
//    (half-wave per edge, lane handles a bf16 pair = 2 cols).
//    out = sigmoid(acc * norm_dst + b).
// ---------------------------------------------------------------------------
__global__ __launch_bounds__(256) void gather_kernel(const int* __restrict__ ptrB,
                                                     const int* __restrict__ indeg,
                                                     const int* __restrict__ sorted_src,
                                                     const ushort* __restrict__ h,
                                                     const float* __restrict__ b,
                                                     float* __restrict__ out) {
    const int lane = threadIdx.x & 63;
    const int half = lane >> 5;
    const int cl = lane & 31;          // col pair index: cols cl*2, cl*2+1
    int nid = (int)((blockIdx.x * (size_t)blockDim.x + threadIdx.x) >> 6);
    if (nid >= N_NODES) return;
    nid = __builtin_amdgcn_readfirstlane(nid);

    const int beg = ptrB[nid];
    const int deg = indeg[nid];

    float ax = 0.f, ay = 0.f;
    const int nfull = deg >> 1;        // iterations where both halves valid
    int e = beg + half;
    #pragma unroll 4
    for (int i = 0; i < nfull; ++i) {
        const int s = sorted_src[e];
        e += 2;
        const uint v = *(const uint*)(h + (size_t)s * OUT_F + cl * 2);
        ax += bf_lo(v);
        ay += bf_hi(v);
    }
    if ((deg & 1) && half == 0) {
        const int s = sorted_src[beg + deg - 1];
        const uint v = *(const uint*)(h + (size_t)s * OUT_F + cl * 2);
        ax += bf_lo(v);
        ay += bf_hi(v);
    }
    // cross-half reduce (edge-parallel halves hold partial sums of same cols)
    ax += __shfl_xor(ax, 32, 64);
    ay += __shfl_xor(ay, 32, 64);

    if (half == 0) {
        const float norm = rsqrtf(fmaxf((float)deg, 1.0f));
        const float x0 = ax * norm + b[cl * 2 + 0];
        const float x1 = ay * norm + b[cl * 2 + 1];
        float2 o;
        o.x = 1.0f / (1.0f + expf(-x0));
        o.y = 1.0f / (1.0f + expf(-x1));
        *(float2*)(out + (size_t)nid * OUT_F + cl * 2) = o;
    }
}

// ---------------------------------------------------------------------------
extern "C" void kernel_launch(void* const* d_in, const int* in_sizes, int n_in,
                              void* d_out, int out_size, void* d_ws, size_t ws_size,
                              hipStream_t stream) {
    const float* feat = (const float*)d_in[0];
    const int* src    = (const int*)d_in[1];
    const int* dst    = (const int*)d_in[2];
    const float* W    = (const float*)d_in[3];
    const float* b    = (const float*)d_in[4];
    float* out = (float*)d_out;

    char* ws = (char*)d_ws;
    size_t off = 0;
    ushort* h = (ushort*)(ws + off);        off += (size_t)N_NODES * OUT_F * 2;  // 6.4 MB bf16
    int* outdeg = (int*)(ws + off);         off += (size_t)N_NODES * 4;
    int* indeg = (int*)(ws + off);          off += (size_t)N_NODES * 4;
    int* counter = (int*)(ws + off);        off += 16;
    int* ptrB = (int*)(ws + off);           off += (size_t)N_NODES * 4;
    int* cursor = (int*)(ws + off);         off += (size_t)N_NODES * 4;
    int* sorted_src = (int*)(ws + off);     off += (size_t)N_EDGES * 4;          // 3.2 MB

    // Zero outdeg, indeg, counter (contiguous).
    hipMemsetAsync(outdeg, 0, (size_t)2 * N_NODES * 4 + 16, stream);

    deg_kernel<<<(N_EDGES + 255) / 256, 256, 0, stream>>>(src, dst, outdeg, indeg);

    alloc_kernel<<<(N_NODES + 255) / 256, 256, 0, stream>>>(indeg, ptrB, cursor, counter);

    sort_kernel<<<(N_EDGES + 255) / 256, 256, 0, stream>>>(src, dst, cursor, sorted_src);

    gemm_kernel<<<(N_NODES + 63) / 64, 256, 0, stream>>>(feat, W, outdeg, h);

    gather_kernel<<<(N_NODES * 64 + 255) / 256, 256, 0, stream>>>(ptrB, indeg, sorted_src, h, b, out);
}

// Round 5
// 176.926 us; speedup vs baseline: 1.6955x; 1.6955x over previous
//
#include <hip/hip_runtime.h>
#include <hip/hip_bf16.h>
#include <math.h>

#define N_NODES 50000
#define N_EDGES 800000
#define IN_F 256
#define OUT_F 64

typedef __attribute__((ext_vector_type(8))) short bf16x8;
typedef __attribute__((ext_vector_type(4))) float f32x4;

__device__ __forceinline__ ushort f2bf(float x) {
    __hip_bfloat16 b = __float2bfloat16(x);   // RNE
    return *reinterpret_cast<ushort*>(&b);
}
__device__ __forceinline__ float bf_lo(uint v) { return __uint_as_float(v << 16); }
__device__ __forceinline__ float bf_hi(uint v) { return __uint_as_float(v & 0xffff0000u); }

// ---------------------------------------------------------------------------
// 1) Degree counting: one thread per edge, int atomics.
// ---------------------------------------------------------------------------
__global__ __launch_bounds__(256) void deg_kernel(const int* __restrict__ src,
                                                  const int* __restrict__ dst,
                                                  int* __restrict__ outdeg,
                                                  int* __restrict__ indeg) {
    int i = blockIdx.x * blockDim.x + threadIdx.x;
    if (i < N_EDGES) {
        atomicAdd(&outdeg[src[i]], 1);
        atomicAdd(&indeg[dst[i]], 1);
    }
}

// ---------------------------------------------------------------------------
// 2) Bucket allocation: wave prefix-sum of indeg + one atomicAdd per wave.
//    Bucket order is arbitrary; gather only needs [beg, beg+deg).
// ---------------------------------------------------------------------------
__global__ __launch_bounds__(256) void alloc_kernel(const int* __restrict__ indeg,
                                                    int* __restrict__ ptrB,
                                                    int* __restrict__ cursor,
                                                    int* __restrict__ counter) {
    const int i = blockIdx.x * blockDim.x + threadIdx.x;
    const int lane = threadIdx.x & 63;
    const int v = (i < N_NODES) ? indeg[i] : 0;
    int incl = v;
    #pragma unroll
    for (int d = 1; d < 64; d <<= 1) {
        int u = __shfl_up(incl, d, 64);
        if (lane >= d) incl += u;
    }
    int base = 0;
    if (lane == 63) base = atomicAdd(counter, incl);
    base = __shfl(base, 63, 64);
    const int beg = base + incl - v;
    if (i < N_NODES) { ptrB[i] = beg; cursor[i] = beg; }
}

// ---------------------------------------------------------------------------
// 3) Bucket edges by dst: sorted_src[cursor[d]++] = src.
// ---------------------------------------------------------------------------
__global__ __launch_bounds__(256) void sort_kernel(const int* __restrict__ src,
                                                   const int* __restrict__ dst,
                                                   int* __restrict__ cursor,
                                                   int* __restrict__ sorted_src) {
    int e = blockIdx.x * blockDim.x + threadIdx.x;
    if (e < N_EDGES) {
        const int d = dst[e];
        const int idx = atomicAdd(&cursor[d], 1);
        sorted_src[idx] = src[e];
    }
}

// ---------------------------------------------------------------------------
// 4) h = bf16( norm_src * (feat @ W) ) via MFMA 16x16x32 bf16.
//    Wave = 64 rows x 64 cols (4 row-tiles x 4 col-tiles); block = 4 waves
//    = 256 rows; grid = 196. feat/W converted to bf16 in-register.
//    A-frag: row = lane&15, k = (lane>>4)*8 + j   (per-step 16 rows x 128B
//    contiguous segments -> cache-line coalesced).
//    C-frag: col = lane&15, row = (lane>>4)*4 + reg   [m89 verified].
// ---------------------------------------------------------------------------
__global__ __launch_bounds__(256) void gemm_kernel(const float* __restrict__ feat,
                                                   const float* __restrict__ W,
                                                   const int* __restrict__ outdeg,
                                                   ushort* __restrict__ h) {
    const int lane = threadIdx.x & 63;
    const int wave = threadIdx.x >> 6;
    const int m = lane & 15;
    const int g = lane >> 4;
    const int rowBase = blockIdx.x * 256 + wave * 64;

    f32x4 acc[4][4];
    #pragma unroll
    for (int rt = 0; rt < 4; ++rt)
        #pragma unroll
        for (int ct = 0; ct < 4; ++ct)
            acc[rt][ct] = (f32x4){0.f, 0.f, 0.f, 0.f};

    #pragma unroll 2
    for (int step = 0; step < 8; ++step) {
        const int k0 = step * 32 + g * 8;   // this lane's k-slice base

        // B frags: W[k0+j][ct*16+m], j=0..7
        bf16x8 bfr[4];
        #pragma unroll
        for (int ct = 0; ct < 4; ++ct) {
            const float* wp = W + (size_t)k0 * OUT_F + ct * 16 + m;
            bf16x8 bb;
            #pragma unroll
            for (int j = 0; j < 8; ++j) bb[j] = (short)f2bf(wp[(size_t)j * OUT_F]);
            bfr[ct] = bb;
        }

        #pragma unroll
        for (int rt = 0; rt < 4; ++rt) {
            int row = rowBase + rt * 16 + m;
            if (row >= N_NODES) row = 0;        // clamp; stores guarded below
            const float* ap = feat + (size_t)row * IN_F + k0;
            const float4 a0 = *(const float4*)ap;
            const float4 a1 = *(const float4*)(ap + 4);
            bf16x8 aa;
            aa[0] = (short)f2bf(a0.x); aa[1] = (short)f2bf(a0.y);
            aa[2] = (short)f2bf(a0.z); aa[3] = (short)f2bf(a0.w);
            aa[4] = (short)f2bf(a1.x); aa[5] = (short)f2bf(a1.y);
            aa[6] = (short)f2bf(a1.z); aa[7] = (short)f2bf(a1.w);
            #pragma unroll
            for (int ct = 0; ct < 4; ++ct)
                acc[rt][ct] = __builtin_amdgcn_mfma_f32_16x16x32_bf16(
                    aa, bfr[ct], acc[rt][ct], 0, 0, 0);
        }
    }

    // Store: reg j of acc[rt][ct] -> row = rowBase + rt*16 + g*4 + j, col = ct*16 + m
    #pragma unroll
    for (int rt = 0; rt < 4; ++rt) {
        #pragma unroll
        for (int j = 0; j < 4; ++j) {
            const int row = rowBase + rt * 16 + g * 4 + j;
            if (row < N_NODES) {
                const float norm = rsqrtf(fmaxf((float)outdeg[row], 1.0f));
                #pragma unroll
                for (int ct = 0; ct < 4; ++ct)
                    h[(size_t)row * OUT_F + ct * 16 + m] = f2bf(acc[rt][ct][j] * norm);
            }
        }
    }
}

// ---------------------------------------------------------------------------
// 5) Gather + epilogue: one wave per dst node, 2 edges per iteration
//    (half-wave per edge, lane handles a bf16 pair = 2 cols).
//    out = sigmoid(acc * norm_dst + b).
// ---------------------------------------------------------------------------
__global__ __launch_bounds__(256) void gather_kernel(const int* __restrict__ ptrB,
                                                     const int* __restrict__ indeg,
                                                     const int* __restrict__ sorted_src,
                                                     const ushort* __restrict__ h,
                                                     const float* __restrict__ b,
                                                     float* __restrict__ out) {
    const int lane = threadIdx.x & 63;
    const int half = lane >> 5;
    const int cl = lane & 31;          // col pair index: cols cl*2, cl*2+1
    int nid = (int)((blockIdx.x * (size_t)blockDim.x + threadIdx.x) >> 6);
    if (nid >= N_NODES) return;
    nid = __builtin_amdgcn_readfirstlane(nid);

    const int beg = ptrB[nid];
    const int deg = indeg[nid];

    float ax = 0.f, ay = 0.f;
    const int nfull = deg >> 1;
    int e = beg + half;
    #pragma unroll 4
    for (int i = 0; i < nfull; ++i) {
        const int s = sorted_src[e];
        e += 2;
        const uint v = *(const uint*)(h + (size_t)s * OUT_F + cl * 2);
        ax += bf_lo(v);
        ay += bf_hi(v);
    }
    if ((deg & 1) && half == 0) {
        const int s = sorted_src[beg + deg - 1];
        const uint v = *(const uint*)(h + (size_t)s * OUT_F + cl * 2);
        ax += bf_lo(v);
        ay += bf_hi(v);
    }
    ax += __shfl_xor(ax, 32, 64);
    ay += __shfl_xor(ay, 32, 64);

    if (half == 0) {
        const float norm = rsqrtf(fmaxf((float)deg, 1.0f));
        const float x0 = ax * norm + b[cl * 2 + 0];
        const float x1 = ay * norm + b[cl * 2 + 1];
        float2 o;
        o.x = 1.0f / (1.0f + expf(-x0));
        o.y = 1.0f / (1.0f + expf(-x1));
        *(float2*)(out + (size_t)nid * OUT_F + cl * 2) = o;
    }
}

// ---------------------------------------------------------------------------
extern "C" void kernel_launch(void* const* d_in, const int* in_sizes, int n_in,
                              void* d_out, int out_size, void* d_ws, size_t ws_size,
                              hipStream_t stream) {
    const float* feat = (const float*)d_in[0];
    const int* src    = (const int*)d_in[1];
    const int* dst    = (const int*)d_in[2];
    const float* W    = (const float*)d_in[3];
    const float* b    = (const float*)d_in[4];
    float* out = (float*)d_out;

    char* ws = (char*)d_ws;
    size_t off = 0;
    ushort* h = (ushort*)(ws + off);        off += (size_t)N_NODES * OUT_F * 2;  // 6.4 MB bf16
    int* outdeg = (int*)(ws + off);         off += (size_t)N_NODES * 4;
    int* indeg = (int*)(ws + off);          off += (size_t)N_NODES * 4;
    int* counter = (int*)(ws + off);        off += 16;
    int* ptrB = (int*)(ws + off);           off += (size_t)N_NODES * 4;
    int* cursor = (int*)(ws + off);         off += (size_t)N_NODES * 4;
    int* sorted_src = (int*)(ws + off);     off += (size_t)N_EDGES * 4;          // 3.2 MB

    // Zero outdeg, indeg, counter (contiguous).
    hipMemsetAsync(outdeg, 0, (size_t)2 * N_NODES * 4 + 16, stream);

    deg_kernel<<<(N_EDGES + 255) / 256, 256, 0, stream>>>(src, dst, outdeg, indeg);

    alloc_kernel<<<(N_NODES + 255) / 256, 256, 0, stream>>>(indeg, ptrB, cursor, counter);

    sort_kernel<<<(N_EDGES + 255) / 256, 256, 0, stream>>>(src, dst, cursor, sorted_src);

    gemm_kernel<<<(N_NODES + 255) / 256, 256, 0, stream>>>(feat, W, outdeg, h);

    gather_kernel<<<(N_NODES * 64 + 255) / 256, 256, 0, stream>>>(ptrB, indeg, sorted_src, h, b, out);
}

// Round 6
// 131.313 us; speedup vs baseline: 2.2844x; 1.3474x over previous
//
#include <hip/hip_runtime.h>
#include <hip/hip_bf16.h>
#include <math.h>

#define N_NODES 50000
#define N_EDGES 800000
#define IN_F 256
#define OUT_F 64

#define HIST_CHUNK 12500   // nodes per LDS histogram chunk (4 chunks)
#define HIST_SLICES 16     // edge slices per (array, chunk)

typedef __attribute__((ext_vector_type(8))) short bf16x8;
typedef __attribute__((ext_vector_type(4))) float f32x4;

__device__ __forceinline__ ushort f2bf(float x) {
    __hip_bfloat16 b = __float2bfloat16(x);   // RNE
    return *reinterpret_cast<ushort*>(&b);
}
__device__ __forceinline__ float bf_lo(uint v) { return __uint_as_float(v << 16); }
__device__ __forceinline__ float bf_hi(uint v) { return __uint_as_float(v & 0xffff0000u); }

// ---------------------------------------------------------------------------
// 1) Degree counting via LDS-privatized histograms.
//    blockIdx.x = arr(2) x chunk(4) x slice(16) = 128 blocks.
//    In-chunk increments hit LDS; flush is CONTIGUOUS global atomics
//    (~782 line-ops per block vs 12.5K random lines) — sidesteps the
//    ~22G line-transactions/s device atomic wall.
// ---------------------------------------------------------------------------
__global__ __launch_bounds__(256) void hist_kernel(const int* __restrict__ src,
                                                   const int* __restrict__ dst,
                                                   int* __restrict__ outdeg,
                                                   int* __restrict__ indeg) {
    __shared__ int cnt[HIST_CHUNK];   // 50 KB
    const int bi = blockIdx.x;
    const int arr = bi >> 6;                 // 0 = src->outdeg, 1 = dst->indeg
    const int chunk = (bi >> 4) & 3;
    const int slice = bi & 15;
    const int* __restrict__ data = arr ? dst : src;
    int* __restrict__ glob = arr ? indeg : outdeg;
    const int base = chunk * HIST_CHUNK;

    for (int i = threadIdx.x; i < HIST_CHUNK; i += 256) cnt[i] = 0;
    __syncthreads();

    // 800K / 16 slices = 50K values = 12.5K int4 per slice.
    const int4* d4 = (const int4*)(data + (size_t)slice * (N_EDGES / HIST_SLICES));
    for (int i = threadIdx.x; i < (N_EDGES / HIST_SLICES) / 4; i += 256) {
        const int4 v = d4[i];
        int r;
        r = v.x - base; if ((unsigned)r < (unsigned)HIST_CHUNK) atomicAdd(&cnt[r], 1);
        r = v.y - base; if ((unsigned)r < (unsigned)HIST_CHUNK) atomicAdd(&cnt[r], 1);
        r = v.z - base; if ((unsigned)r < (unsigned)HIST_CHUNK) atomicAdd(&cnt[r], 1);
        r = v.w - base; if ((unsigned)r < (unsigned)HIST_CHUNK) atomicAdd(&cnt[r], 1);
    }
    __syncthreads();

    for (int i = threadIdx.x; i < HIST_CHUNK; i += 256) {
        const int c = cnt[i];
        if (c) atomicAdd(&glob[base + i], c);
    }
}

// ---------------------------------------------------------------------------
// 2) Bucket allocation: wave prefix-sum of indeg + one atomicAdd per wave.
// ---------------------------------------------------------------------------
__global__ __launch_bounds__(256) void alloc_kernel(const int* __restrict__ indeg,
                                                    int* __restrict__ ptrB,
                                                    int* __restrict__ cursor,
                                                    int* __restrict__ counter) {
    const int i = blockIdx.x * blockDim.x + threadIdx.x;
    const int lane = threadIdx.x & 63;
    const int v = (i < N_NODES) ? indeg[i] : 0;
    int incl = v;
    #pragma unroll
    for (int d = 1; d < 64; d <<= 1) {
        int u = __shfl_up(incl, d, 64);
        if (lane >= d) incl += u;
    }
    int base = 0;
    if (lane == 63) base = atomicAdd(counter, incl);
    base = __shfl(base, 63, 64);
    const int beg = base + incl - v;
    if (i < N_NODES) { ptrB[i] = beg; cursor[i] = beg; }
}

// ---------------------------------------------------------------------------
// 3) Bucket edges by dst: sorted_src[cursor[d]++] = src.
// ---------------------------------------------------------------------------
__global__ __launch_bounds__(256) void sort_kernel(const int* __restrict__ src,
                                                   const int* __restrict__ dst,
                                                   int* __restrict__ cursor,
                                                   int* __restrict__ sorted_src) {
    int e = blockIdx.x * blockDim.x + threadIdx.x;
    if (e < N_EDGES) {
        const int d = dst[e];
        const int idx = atomicAdd(&cursor[d], 1);
        sorted_src[idx] = src[e];
    }
}

// ---------------------------------------------------------------------------
// 4) h = bf16( norm_src * (feat @ W) ) via MFMA 16x16x32 bf16.
//    Wave = 64 rows x 64 cols; block = 4 waves = 256 rows; grid = 196.
//    C-frag: col = lane&15, row = (lane>>4)*4 + reg   [m89 verified].
// ---------------------------------------------------------------------------
__global__ __launch_bounds__(256) void gemm_kernel(const float* __restrict__ feat,
                                                   const float* __restrict__ W,
                                                   const int* __restrict__ outdeg,
                                                   ushort* __restrict__ h) {
    const int lane = threadIdx.x & 63;
    const int wave = threadIdx.x >> 6;
    const int m = lane & 15;
    const int g = lane >> 4;
    const int rowBase = blockIdx.x * 256 + wave * 64;

    f32x4 acc[4][4];
    #pragma unroll
    for (int rt = 0; rt < 4; ++rt)
        #pragma unroll
        for (int ct = 0; ct < 4; ++ct)
            acc[rt][ct] = (f32x4){0.f, 0.f, 0.f, 0.f};

    #pragma unroll 2
    for (int step = 0; step < 8; ++step) {
        const int k0 = step * 32 + g * 8;

        bf16x8 bfr[4];
        #pragma unroll
        for (int ct = 0; ct < 4; ++ct) {
            const float* wp = W + (size_t)k0 * OUT_F + ct * 16 + m;
            bf16x8 bb;
            #pragma unroll
            for (int j = 0; j < 8; ++j) bb[j] = (short)f2bf(wp[(size_t)j * OUT_F]);
            bfr[ct] = bb;
        }

        #pragma unroll
        for (int rt = 0; rt < 4; ++rt) {
            int row = rowBase + rt * 16 + m;
            if (row >= N_NODES) row = 0;
            const float* ap = feat + (size_t)row * IN_F + k0;
            const float4 a0 = *(const float4*)ap;
            const float4 a1 = *(const float4*)(ap + 4);
            bf16x8 aa;
            aa[0] = (short)f2bf(a0.x); aa[1] = (short)f2bf(a0.y);
            aa[2] = (short)f2bf(a0.z); aa[3] = (short)f2bf(a0.w);
            aa[4] = (short)f2bf(a1.x); aa[5] = (short)f2bf(a1.y);
            aa[6] = (short)f2bf(a1.z); aa[7] = (short)f2bf(a1.w);
            #pragma unroll
            for (int ct = 0; ct < 4; ++ct)
                acc[rt][ct] = __builtin_amdgcn_mfma_f32_16x16x32_bf16(
                    aa, bfr[ct], acc[rt][ct], 0, 0, 0);
        }
    }

    #pragma unroll
    for (int rt = 0; rt < 4; ++rt) {
        #pragma unroll
        for (int j = 0; j < 4; ++j) {
            const int row = rowBase + rt * 16 + g * 4 + j;
            if (row < N_NODES) {
                const float norm = rsqrtf(fmaxf((float)outdeg[row], 1.0f));
                #pragma unroll
                for (int ct = 0; ct < 4; ++ct)
                    h[(size_t)row * OUT_F + ct * 16 + m] = f2bf(acc[rt][ct][j] * norm);
            }
        }
    }
}

// ---------------------------------------------------------------------------
// 5) Gather + epilogue: one wave per dst node, 2 edges per iteration
//    (half-wave per edge, lane handles a bf16 pair = 2 cols).
// ---------------------------------------------------------------------------
__global__ __launch_bounds__(256) void gather_kernel(const int* __restrict__ ptrB,
                                                     const int* __restrict__ indeg,
                                                     const int* __restrict__ sorted_src,
                                                     const ushort* __restrict__ h,
                                                     const float* __restrict__ b,
                                                     float* __restrict__ out) {
    const int lane = threadIdx.x & 63;
    const int half = lane >> 5;
    const int cl = lane & 31;
    int nid = (int)((blockIdx.x * (size_t)blockDim.x + threadIdx.x) >> 6);
    if (nid >= N_NODES) return;
    nid = __builtin_amdgcn_readfirstlane(nid);

    const int beg = ptrB[nid];
    const int deg = indeg[nid];

    float ax = 0.f, ay = 0.f;
    const int nfull = deg >> 1;
    int e = beg + half;
    #pragma unroll 4
    for (int i = 0; i < nfull; ++i) {
        const int s = sorted_src[e];
        e += 2;
        const uint v = *(const uint*)(h + (size_t)s * OUT_F + cl * 2);
        ax += bf_lo(v);
        ay += bf_hi(v);
    }
    if ((deg & 1) && half == 0) {
        const int s = sorted_src[beg + deg - 1];
        const uint v = *(const uint*)(h + (size_t)s * OUT_F + cl * 2);
        ax += bf_lo(v);
        ay += bf_hi(v);
    }
    ax += __shfl_xor(ax, 32, 64);
    ay += __shfl_xor(ay, 32, 64);

    if (half == 0) {
        const float norm = rsqrtf(fmaxf((float)deg, 1.0f));
        const float x0 = ax * norm + b[cl * 2 + 0];
        const float x1 = ay * norm + b[cl * 2 + 1];
        float2 o;
        o.x = 1.0f / (1.0f + expf(-x0));
        o.y = 1.0f / (1.0f + expf(-x1));
        *(float2*)(out + (size_t)nid * OUT_F + cl * 2) = o;
    }
}

// ---------------------------------------------------------------------------
extern "C" void kernel_launch(void* const* d_in, const int* in_sizes, int n_in,
                              void* d_out, int out_size, void* d_ws, size_t ws_size,
                              hipStream_t stream) {
    const float* feat = (const float*)d_in[0];
    const int* src    = (const int*)d_in[1];
    const int* dst    = (const int*)d_in[2];
    const float* W    = (const float*)d_in[3];
    const float* b    = (const float*)d_in[4];
    float* out = (float*)d_out;

    char* ws = (char*)d_ws;
    size_t off = 0;
    ushort* h = (ushort*)(ws + off);        off += (size_t)N_NODES * OUT_F * 2;  // 6.4 MB bf16
    int* outdeg = (int*)(ws + off);         off += (size_t)N_NODES * 4;
    int* indeg = (int*)(ws + off);          off += (size_t)N_NODES * 4;
    int* counter = (int*)(ws + off);        off += 16;
    int* ptrB = (int*)(ws + off);           off += (size_t)N_NODES * 4;
    int* cursor = (int*)(ws + off);         off += (size_t)N_NODES * 4;
    int* sorted_src = (int*)(ws + off);     off += (size_t)N_EDGES * 4;          // 3.2 MB

    // Zero outdeg, indeg, counter (contiguous) — hist flush accumulates.
    hipMemsetAsync(outdeg, 0, (size_t)2 * N_NODES * 4 + 16, stream);

    hist_kernel<<<128, 256, 0, stream>>>(src, dst, outdeg, indeg);

    alloc_kernel<<<(N_NODES + 255) / 256, 256, 0, stream>>>(indeg, ptrB, cursor, counter);

    sort_kernel<<<(N_EDGES + 255) / 256, 256, 0, stream>>>(src, dst, cursor, sorted_src);

    gemm_kernel<<<(N_NODES + 255) / 256, 256, 0, stream>>>(feat, W, outdeg, h);

    gather_kernel<<<(N_NODES * 64 + 255) / 256, 256, 0, stream>>>(ptrB, indeg, sorted_src, h, b, out);
}

// Round 7
// 102.134 us; speedup vs baseline: 2.9371x; 1.2857x over previous
//
#include <hip/hip_runtime.h>
#include <hip/hip_bf16.h>
#include <math.h>

#define N_NODES 50000
#define N_EDGES 800000
#define IN_F 256
#define OUT_F 64

#define HIST_CHUNK 12500   // nodes per LDS histogram chunk (4 chunks)
#define HIST_SLICES 16     // edge slices per (array, chunk)

#define BKT 256            // nodes per dst-bucket
#define NB 196             // ceil(50000/256)
#define PARTA_BLOCKS 200   // edge slices in pass A (800000/200 = 4000/block)

typedef __attribute__((ext_vector_type(8))) short bf16x8;
typedef __attribute__((ext_vector_type(4))) float f32x4;

__device__ __forceinline__ ushort f2bf(float x) {
    __hip_bfloat16 b = __float2bfloat16(x);   // RNE
    return *reinterpret_cast<ushort*>(&b);
}
__device__ __forceinline__ float bf_lo(uint v) { return __uint_as_float(v << 16); }
__device__ __forceinline__ float bf_hi(uint v) { return __uint_as_float(v & 0xffff0000u); }

// ---------------------------------------------------------------------------
// 1) Degree counting via LDS-privatized histograms (round-6, kept).
// ---------------------------------------------------------------------------
__global__ __launch_bounds__(256) void hist_kernel(const int* __restrict__ src,
                                                   const int* __restrict__ dst,
                                                   int* __restrict__ outdeg,
                                                   int* __restrict__ indeg) {
    __shared__ int cnt[HIST_CHUNK];   // 50 KB
    const int bi = blockIdx.x;
    const int arr = bi >> 6;
    const int chunk = (bi >> 4) & 3;
    const int slice = bi & 15;
    const int* __restrict__ data = arr ? dst : src;
    int* __restrict__ glob = arr ? indeg : outdeg;
    const int base = chunk * HIST_CHUNK;

    for (int i = threadIdx.x; i < HIST_CHUNK; i += 256) cnt[i] = 0;
    __syncthreads();

    const int4* d4 = (const int4*)(data + (size_t)slice * (N_EDGES / HIST_SLICES));
    for (int i = threadIdx.x; i < (N_EDGES / HIST_SLICES) / 4; i += 256) {
        const int4 v = d4[i];
        int r;
        r = v.x - base; if ((unsigned)r < (unsigned)HIST_CHUNK) atomicAdd(&cnt[r], 1);
        r = v.y - base; if ((unsigned)r < (unsigned)HIST_CHUNK) atomicAdd(&cnt[r], 1);
        r = v.z - base; if ((unsigned)r < (unsigned)HIST_CHUNK) atomicAdd(&cnt[r], 1);
        r = v.w - base; if ((unsigned)r < (unsigned)HIST_CHUNK) atomicAdd(&cnt[r], 1);
    }
    __syncthreads();

    for (int i = threadIdx.x; i < HIST_CHUNK; i += 256) {
        const int c = cnt[i];
        if (c) atomicAdd(&glob[base + i], c);
    }
}

// ---------------------------------------------------------------------------
// 2) Bucket-ordered allocation: one block per 256-node bucket. Intra-block
//    exclusive scan of indeg; ONE global atomicAdd per bucket. Node regions
//    are contiguous within a bucket (required by pass B); bucket order is
//    arbitrary (gather doesn't care).
// ---------------------------------------------------------------------------
__global__ __launch_bounds__(256) void alloc_kernel(const int* __restrict__ indeg,
                                                    int* __restrict__ ptr,
                                                    int* __restrict__ bucketBase,
                                                    int* __restrict__ gcursor,
                                                    int* __restrict__ counter) {
    __shared__ int wtot[4];
    __shared__ int sbase;
    const int b = blockIdx.x;
    const int tid = threadIdx.x;
    const int lane = tid & 63;
    const int wave = tid >> 6;
    const int node = b * BKT + tid;
    const int v = (node < N_NODES) ? indeg[node] : 0;
    int incl = v;
    #pragma unroll
    for (int d = 1; d < 64; d <<= 1) {
        int u = __shfl_up(incl, d, 64);
        if (lane >= d) incl += u;
    }
    if (lane == 63) wtot[wave] = incl;
    __syncthreads();
    int woff = 0, total = 0;
    #pragma unroll
    for (int w = 0; w < 4; ++w) {
        const int t = wtot[w];
        if (w < wave) woff += t;
        total += t;
    }
    if (tid == 0) sbase = atomicAdd(counter, total);
    __syncthreads();
    const int base = sbase;
    if (node < N_NODES) ptr[node] = base + woff + incl - v;
    if (tid == 0) { bucketBase[b] = base; gcursor[b] = base; }
}

// ---------------------------------------------------------------------------
// 3a) Pass A: partition edges into 196 dst-buckets, packed as
//     (dst&255)<<16 | src  (src<65536, local<256). Count-then-place:
//     per-block per-bucket runs are contiguous -> writes combine.
// ---------------------------------------------------------------------------
__global__ __launch_bounds__(256) void partA_kernel(const int* __restrict__ src,
                                                    const int* __restrict__ dst,
                                                    int* __restrict__ gcursor,
                                                    uint* __restrict__ pairs) {
    __shared__ int lcnt[NB];
    __shared__ int lbase[NB];
    const int tid = threadIdx.x;
    const int EPB = N_EDGES / PARTA_BLOCKS;   // 4000
    const int n4 = EPB / 4;                   // 1000

    for (int i = tid; i < NB; i += 256) lcnt[i] = 0;
    __syncthreads();

    const int4* t4 = (const int4*)(dst + (size_t)blockIdx.x * EPB);
    const int4* s4 = (const int4*)(src + (size_t)blockIdx.x * EPB);

    for (int i = tid; i < n4; i += 256) {
        const int4 d = t4[i];
        atomicAdd(&lcnt[d.x >> 8], 1);
        atomicAdd(&lcnt[d.y >> 8], 1);
        atomicAdd(&lcnt[d.z >> 8], 1);
        atomicAdd(&lcnt[d.w >> 8], 1);
    }
    __syncthreads();

    for (int i = tid; i < NB; i += 256) {
        const int c = lcnt[i];
        lbase[i] = c ? atomicAdd(&gcursor[i], c) : 0;
        lcnt[i] = 0;
    }
    __syncthreads();

    for (int i = tid; i < n4; i += 256) {
        const int4 d = t4[i];
        const int4 s = s4[i];
        int bx, off;
        bx = d.x >> 8; off = atomicAdd(&lcnt[bx], 1);
        pairs[lbase[bx] + off] = ((uint)(d.x & 255) << 16) | (uint)s.x;
        bx = d.y >> 8; off = atomicAdd(&lcnt[bx], 1);
        pairs[lbase[bx] + off] = ((uint)(d.y & 255) << 16) | (uint)s.y;
        bx = d.z >> 8; off = atomicAdd(&lcnt[bx], 1);
        pairs[lbase[bx] + off] = ((uint)(d.z & 255) << 16) | (uint)s.z;
        bx = d.w >> 8; off = atomicAdd(&lcnt[bx], 1);
        pairs[lbase[bx] + off] = ((uint)(d.w & 255) << 16) | (uint)s.w;
    }
}

// ---------------------------------------------------------------------------
// 3b) Pass B: within one bucket, place each src at ptr[dst]+pos via LDS
//     cursors. Scatter stays inside the bucket's ~16 KB fully-written
//     region -> write-combines in cache.
// ---------------------------------------------------------------------------
__global__ __launch_bounds__(256) void partB_kernel(const uint* __restrict__ pairs,
                                                    const int* __restrict__ ptr,
                                                    const int* __restrict__ bucketBase,
                                                    const int* __restrict__ gcursor,
                                                    int* __restrict__ sorted_src) {
    __shared__ int lptr[BKT];
    __shared__ int lcur[BKT];
    const int b = blockIdx.x;
    const int tid = threadIdx.x;
    const int node = b * BKT + tid;
    lptr[tid] = (node < N_NODES) ? ptr[node] : 0;
    lcur[tid] = 0;
    __syncthreads();
    const int base = bucketBase[b];
    const int cnt = gcursor[b] - base;
    for (int i = tid; i < cnt; i += 256) {
        const uint p = pairs[base + i];
        const int local = (int)(p >> 16);
        const int pos = atomicAdd(&lcur[local], 1);
        sorted_src[lptr[local] + pos] = (int)(p & 0xFFFFu);
    }
}

// ---------------------------------------------------------------------------
// 4) h = bf16( norm_src * (feat @ W) ) via MFMA 16x16x32 bf16 (round-5).
// ---------------------------------------------------------------------------
__global__ __launch_bounds__(256) void gemm_kernel(const float* __restrict__ feat,
                                                   const float* __restrict__ W,
                                                   const int* __restrict__ outdeg,
                                                   ushort* __restrict__ h) {
    const int lane = threadIdx.x & 63;
    const int wave = threadIdx.x >> 6;
    const int m = lane & 15;
    const int g = lane >> 4;
    const int rowBase = blockIdx.x * 256 + wave * 64;

    f32x4 acc[4][4];
    #pragma unroll
    for (int rt = 0; rt < 4; ++rt)
        #pragma unroll
        for (int ct = 0; ct < 4; ++ct)
            acc[rt][ct] = (f32x4){0.f, 0.f, 0.f, 0.f};

    #pragma unroll 2
    for (int step = 0; step < 8; ++step) {
        const int k0 = step * 32 + g * 8;

        bf16x8 bfr[4];
        #pragma unroll
        for (int ct = 0; ct < 4; ++ct) {
            const float* wp = W + (size_t)k0 * OUT_F + ct * 16 + m;
            bf16x8 bb;
            #pragma unroll
            for (int j = 0; j < 8; ++j) bb[j] = (short)f2bf(wp[(size_t)j * OUT_F]);
            bfr[ct] = bb;
        }

        #pragma unroll
        for (int rt = 0; rt < 4; ++rt) {
            int row = rowBase + rt * 16 + m;
            if (row >= N_NODES) row = 0;
            const float* ap = feat + (size_t)row * IN_F + k0;
            const float4 a0 = *(const float4*)ap;
            const float4 a1 = *(const float4*)(ap + 4);
            bf16x8 aa;
            aa[0] = (short)f2bf(a0.x); aa[1] = (short)f2bf(a0.y);
            aa[2] = (short)f2bf(a0.z); aa[3] = (short)f2bf(a0.w);
            aa[4] = (short)f2bf(a1.x); aa[5] = (short)f2bf(a1.y);
            aa[6] = (short)f2bf(a1.z); aa[7] = (short)f2bf(a1.w);
            #pragma unroll
            for (int ct = 0; ct < 4; ++ct)
                acc[rt][ct] = __builtin_amdgcn_mfma_f32_16x16x32_bf16(
                    aa, bfr[ct], acc[rt][ct], 0, 0, 0);
        }
    }

    #pragma unroll
    for (int rt = 0; rt < 4; ++rt) {
        #pragma unroll
        for (int j = 0; j < 4; ++j) {
            const int row = rowBase + rt * 16 + g * 4 + j;
            if (row < N_NODES) {
                const float norm = rsqrtf(fmaxf((float)outdeg[row], 1.0f));
                #pragma unroll
                for (int ct = 0; ct < 4; ++ct)
                    h[(size_t)row * OUT_F + ct * 16 + m] = f2bf(acc[rt][ct][j] * norm);
            }
        }
    }
}

// ---------------------------------------------------------------------------
// 5) Gather + epilogue: one wave per dst node, 2 edges per iteration.
// ---------------------------------------------------------------------------
__global__ __launch_bounds__(256) void gather_kernel(const int* __restrict__ ptr,
                                                     const int* __restrict__ indeg,
                                                     const int* __restrict__ sorted_src,
                                                     const ushort* __restrict__ h,
                                                     const float* __restrict__ b,
                                                     float* __restrict__ out) {
    const int lane = threadIdx.x & 63;
    const int half = lane >> 5;
    const int cl = lane & 31;
    int nid = (int)((blockIdx.x * (size_t)blockDim.x + threadIdx.x) >> 6);
    if (nid >= N_NODES) return;
    nid = __builtin_amdgcn_readfirstlane(nid);

    const int beg = ptr[nid];
    const int deg = indeg[nid];

    float ax = 0.f, ay = 0.f;
    const int nfull = deg >> 1;
    int e = beg + half;
    #pragma unroll 4
    for (int i = 0; i < nfull; ++i) {
        const int s = sorted_src[e];
        e += 2;
        const uint v = *(const uint*)(h + (size_t)s * OUT_F + cl * 2);
        ax += bf_lo(v);
        ay += bf_hi(v);
    }
    if ((deg & 1) && half == 0) {
        const int s = sorted_src[beg + deg - 1];
        const uint v = *(const uint*)(h + (size_t)s * OUT_F + cl * 2);
        ax += bf_lo(v);
        ay += bf_hi(v);
    }
    ax += __shfl_xor(ax, 32, 64);
    ay += __shfl_xor(ay, 32, 64);

    if (half == 0) {
        const float norm = rsqrtf(fmaxf((float)deg, 1.0f));
        const float x0 = ax * norm + b[cl * 2 + 0];
        const float x1 = ay * norm + b[cl * 2 + 1];
        float2 o;
        o.x = 1.0f / (1.0f + expf(-x0));
        o.y = 1.0f / (1.0f + expf(-x1));
        *(float2*)(out + (size_t)nid * OUT_F + cl * 2) = o;
    }
}

// ---------------------------------------------------------------------------
extern "C" void kernel_launch(void* const* d_in, const int* in_sizes, int n_in,
                              void* d_out, int out_size, void* d_ws, size_t ws_size,
                              hipStream_t stream) {
    const float* feat = (const float*)d_in[0];
    const int* src    = (const int*)d_in[1];
    const int* dst    = (const int*)d_in[2];
    const float* W    = (const float*)d_in[3];
    const float* b    = (const float*)d_in[4];
    float* out = (float*)d_out;

    char* ws = (char*)d_ws;
    size_t off = 0;
    ushort* h = (ushort*)(ws + off);        off += (size_t)N_NODES * OUT_F * 2;  // 6.4 MB bf16
    int* outdeg = (int*)(ws + off);         off += (size_t)N_NODES * 4;
    int* indeg = (int*)(ws + off);          off += (size_t)N_NODES * 4;
    int* counter = (int*)(ws + off);        off += 16;
    int* ptr = (int*)(ws + off);            off += (size_t)N_NODES * 4;
    int* bucketBase = (int*)(ws + off);     off += 256 * 4;
    int* gcursor = (int*)(ws + off);        off += 256 * 4;
    uint* pairs = (uint*)(ws + off);        off += (size_t)N_EDGES * 4;          // 3.2 MB
    int* sorted_src = (int*)(ws + off);     off += (size_t)N_EDGES * 4;          // 3.2 MB

    // Zero outdeg, indeg, counter (contiguous).
    hipMemsetAsync(outdeg, 0, (size_t)2 * N_NODES * 4 + 16, stream);

    hist_kernel<<<128, 256, 0, stream>>>(src, dst, outdeg, indeg);

    alloc_kernel<<<NB, 256, 0, stream>>>(indeg, ptr, bucketBase, gcursor, counter);

    partA_kernel<<<PARTA_BLOCKS, 256, 0, stream>>>(src, dst, gcursor, pairs);

    partB_kernel<<<NB, 256, 0, stream>>>(pairs, ptr, bucketBase, gcursor, sorted_src);

    gemm_kernel<<<(N_NODES + 255) / 256, 256, 0, stream>>>(feat, W, outdeg, h);

    gather_kernel<<<(N_NODES * 64 + 255) / 256, 256, 0, stream>>>(ptr, indeg, sorted_src, h, b, out);
}